// Round 3
// baseline (180.632 us; speedup 1.0000x reference)
//
#include <hip/hip_runtime.h>

#define B_IMG 8
#define A_TOTAL 120000
#define C_CLS 80
#define M_ANN 32
#define APB 256      // anchors per block (kernel A)
#define THREADS 256
#define NEG075LN2 (-0.51986038542f)   // -0.75 * ln(2)
#define NF4_PER_IMG (A_TOTAL * (C_CLS / 4))   // 2,400,000 float4 per image
#define BLOCKS_X_B 256                // kernel B x-blocks per image (2048 total)

// ws layout (floats):
//   [0..7]   c_sum per image
//   [8..15]  r_sum per image
//   [16..23] npos per image
//   [32..32+B*A) per-anchor multiplier m (0 = ignore, -0.75*ln2 = active)
#define WS_M_OFF 32

__global__ void init_ws_kernel(float* __restrict__ ws) {
    int i = threadIdx.x;
    if (i < 3 * B_IMG) ws[i] = 0.0f;
}

// ---------------- Kernel A: anchor assignment + GIoU + focal correction ----------------
__global__ __launch_bounds__(THREADS) void assign_kernel(
    const float* __restrict__ cls,      // (B, A, C)
    const float* __restrict__ reg,      // (B, A, 4)
    const float* __restrict__ anchors,  // (A, 4)  [y1,x1,y2,x2]
    const float* __restrict__ ann,      // (B, M, 5) [x1,y1,x2,y2,class]
    float* __restrict__ ws)
{
    __shared__ float red_c[4], red_r[4], red_n[4];

    const int b   = blockIdx.y;
    const int a0  = blockIdx.x * APB;
    const int tid = threadIdx.x;
    const int nA  = min(APB, A_TOTAL - a0);
    const float* __restrict__ annb = ann + b * (M_ANN * 5);  // uniform -> s_load

    float r_acc = 0.0f, n_acc = 0.0f, c_acc = 0.0f;

    if (tid < nA) {
        const int a = a0 + tid;
        float4 anc = ((const float4*)anchors)[a];
        float ay1 = anc.x, ax1 = anc.y, ay2 = anc.z, ax2 = anc.w;
        float area_a = (ay2 - ay1) * (ax2 - ax1);
        float binter = 0.0f, bua = 1.0f;
        int   barg = 0;
        #pragma unroll
        for (int j = 0; j < M_ANN; ++j) {
            float bx1 = annb[j * 5 + 0], by1 = annb[j * 5 + 1];
            float bx2 = annb[j * 5 + 2], by2 = annb[j * 5 + 3];
            float iw = fmaxf(fminf(ax2, bx2) - fmaxf(ax1, bx1), 0.0f);
            float ih = fmaxf(fminf(ay2, by2) - fmaxf(ay1, by1), 0.0f);
            float inter = iw * ih;
            float ua = fmaxf(area_a + (bx2 - bx1) * (by2 - by1) - inter, 1e-8f);
            // iou_j > iou_best  <=>  inter_j * ua_best > inter_best * ua_j  (all >= 0)
            bool gt = inter * bua > binter * ua;
            binter = gt ? inter : binter;
            bua    = gt ? ua    : bua;
            barg   = gt ? j     : barg;   // strict > keeps FIRST max (matches jnp.argmax)
        }
        bool pos = binter >= 0.5f * bua;
        bool neg = binter <  0.4f * bua;
        float mval = (pos || neg) ? NEG075LN2 : 0.0f;   // ignore band -> 0
        ws[WS_M_OFF + (size_t)b * A_TOTAL + a] = mval;

        if (pos) {
            n_acc = 1.0f;
            int k = (int)annb[barg * 5 + 4];
            // focal correction: true class uses pos formula, kernel B applies neg formula
            float cv = cls[((size_t)b * A_TOTAL + a) * C_CLS + k];
            float c  = fminf(fmaxf(cv, 5e-4f), 1.0f - 5e-4f);
            float omc = 1.0f - c;
            c_acc += 0.25f * omc * omc * (-__logf(c))
                   - 0.75f * c * c * (-__logf(omc));

            // regression GIoU loss
            float4 rg = ((const float4*)reg)[(size_t)b * A_TOTAL + a];
            float ty = rg.x, tx = rg.y, th = rg.z, tw = rg.w;
            float aw = ax2 - ax1, ah = ay2 - ay1;
            float acx = ax1 + 0.5f * aw, acy = ay1 + 0.5f * ah;
            float pcx = tx * aw + acx, pcy = ty * ah + acy;
            float pw = __expf(tw) * aw, ph = __expf(th) * ah;
            float px1 = fmaxf(pcx - 0.5f * pw, 0.0f);
            float py1 = fmaxf(pcy - 0.5f * ph, 0.0f);
            float px2 = fmaxf(pcx + 0.5f * pw, 0.0f);
            float py2 = fmaxf(pcy + 0.5f * ph, 0.0f);
            float gx1 = fmaxf(annb[barg * 5 + 0], 0.0f);
            float gy1 = fmaxf(annb[barg * 5 + 1], 0.0f);
            float gx2 = fmaxf(annb[barg * 5 + 2], 0.0f);
            float gy2 = fmaxf(annb[barg * 5 + 3], 0.0f);
            float iw2 = fmaxf(fminf(px2, gx2) - fmaxf(px1, gx1), 0.0f);
            float ih2 = fmaxf(fminf(py2, gy2) - fmaxf(py1, gy1), 0.0f);
            float inter2 = iw2 * ih2;
            float area_p = fmaxf((px2 - px1) * (py2 - py1), 1e-6f);
            float area_g = fmaxf((gx2 - gx1) * (gy2 - gy1), 1e-6f);
            float uni = area_p + area_g - inter2;
            float iou2 = inter2 / (uni + 1e-7f);
            float wc = fmaxf(fmaxf(px2, gx2) - fminf(px1, gx1), 1e-6f);
            float hc = fmaxf(fmaxf(py2, gy2) - fminf(py1, gy1), 1e-6f);
            float area_c = wc * hc;
            float giou = fminf(fmaxf(iou2 - (area_c - uni) / (area_c + 1e-7f), -1.0f), 1.0f);
            r_acc = 1.0f - giou;
        }
    }

    // block reduction + per-image atomics (c correction, r, n)
    #pragma unroll
    for (int o = 32; o > 0; o >>= 1) {
        c_acc += __shfl_down(c_acc, o);
        r_acc += __shfl_down(r_acc, o);
        n_acc += __shfl_down(n_acc, o);
    }
    int wid = tid >> 6;
    if ((tid & 63) == 0) { red_c[wid] = c_acc; red_r[wid] = r_acc; red_n[wid] = n_acc; }
    __syncthreads();
    if (tid == 0) {
        atomicAdd(&ws[b],             red_c[0] + red_c[1] + red_c[2] + red_c[3]);
        atomicAdd(&ws[B_IMG + b],     red_r[0] + red_r[1] + red_r[2] + red_r[3]);
        atomicAdd(&ws[2 * B_IMG + b], red_n[0] + red_n[1] + red_n[2] + red_n[3]);
    }
}

// ---------------- Kernel B: pure streaming focal reduce over classifications ----------------
__global__ __launch_bounds__(THREADS) void focal_stream_kernel(
    const float* __restrict__ cls,      // (B, A, C)
    const float* __restrict__ ws_m,     // per-anchor multiplier, B*A floats
    float* __restrict__ ws)
{
    __shared__ float red_c[4];

    const int b   = blockIdx.y;
    const int tid = threadIdx.x;
    const float4* __restrict__ cp = (const float4*)(cls + (size_t)b * A_TOTAL * C_CLS);
    const float*  __restrict__ mb = ws_m + (size_t)b * A_TOTAL;

    float c_acc = 0.0f;
    for (unsigned i = blockIdx.x * THREADS + tid; i < (unsigned)NF4_PER_IMG;
         i += BLOCKS_X_B * THREADS) {
        float4 v = cp[i];
        float m = mb[i / 20u];          // 20 float4 per anchor; L1/L2 hit
        float s;
        float c = fminf(fmaxf(v.x, 5e-4f), 1.0f - 5e-4f);
        s = c * c * __log2f(1.0f - c);
        c = fminf(fmaxf(v.y, 5e-4f), 1.0f - 5e-4f);
        s = fmaf(c * c, __log2f(1.0f - c), s);
        c = fminf(fmaxf(v.z, 5e-4f), 1.0f - 5e-4f);
        s = fmaf(c * c, __log2f(1.0f - c), s);
        c = fminf(fmaxf(v.w, 5e-4f), 1.0f - 5e-4f);
        s = fmaf(c * c, __log2f(1.0f - c), s);
        c_acc = fmaf(m, s, c_acc);      // m = -0.75*ln2 (active) or 0 (ignore)
    }

    #pragma unroll
    for (int o = 32; o > 0; o >>= 1) c_acc += __shfl_down(c_acc, o);
    int wid = tid >> 6;
    if ((tid & 63) == 0) red_c[wid] = c_acc;
    __syncthreads();
    if (tid == 0)
        atomicAdd(&ws[b], red_c[0] + red_c[1] + red_c[2] + red_c[3]);
}

__global__ void finalize_kernel(const float* __restrict__ ws, float* __restrict__ out) {
    if (threadIdx.x == 0) {
        float c = 0.0f, r = 0.0f;
        for (int b = 0; b < B_IMG; ++b) {
            float n = ws[2 * B_IMG + b];
            c += ws[b] / fmaxf(n, 1.0f);
            r += (n > 0.0f) ? (ws[B_IMG + b] / fmaxf(n, 1.0f)) : 0.0f;
        }
        c *= (1.0f / B_IMG);
        r *= (1.0f / B_IMG);
        out[0] = c + r;
        out[1] = c;
        out[2] = r;
    }
}

extern "C" void kernel_launch(void* const* d_in, const int* in_sizes, int n_in,
                              void* d_out, int out_size, void* d_ws, size_t ws_size,
                              hipStream_t stream) {
    const float* cls     = (const float*)d_in[0];
    const float* reg     = (const float*)d_in[1];
    const float* anchors = (const float*)d_in[2];
    const float* ann     = (const float*)d_in[3];
    float* ws  = (float*)d_ws;
    float* out = (float*)d_out;

    hipLaunchKernelGGL(init_ws_kernel, dim3(1), dim3(64), 0, stream, ws);
    dim3 gridA((A_TOTAL + APB - 1) / APB, B_IMG);
    hipLaunchKernelGGL(assign_kernel, gridA, dim3(THREADS), 0, stream,
                       cls, reg, anchors, ann, ws);
    dim3 gridB(BLOCKS_X_B, B_IMG);
    hipLaunchKernelGGL(focal_stream_kernel, gridB, dim3(THREADS), 0, stream,
                       cls, ws + WS_M_OFF, ws);
    hipLaunchKernelGGL(finalize_kernel, dim3(1), dim3(64), 0, stream, ws, out);
}

// Round 4
// 127.440 us; speedup vs baseline: 1.4174x; 1.4174x over previous
//
#include <hip/hip_runtime.h>

#define B_IMG 8
#define A_TOTAL 120000
#define C_CLS 80
#define M_ANN 32
#define APB 256      // anchors per block
#define THREADS 256
#define NEG075LN2 (-0.51986038542f)   // -0.75 * ln(2)

// ws layout (floats): [0..7] c_sum per image, [8..15] r_sum, [16..23] npos
__global__ void init_ws_kernel(float* __restrict__ ws) {
    int i = threadIdx.x;
    if (i < 3 * B_IMG) ws[i] = 0.0f;
}

__global__ __launch_bounds__(THREADS) void focal_main_kernel(
    const float* __restrict__ cls,      // (B, A, C)
    const float* __restrict__ reg,      // (B, A, 4)
    const float* __restrict__ anchors,  // (A, 4)  [y1,x1,y2,x2]
    const float* __restrict__ ann,      // (B, M, 5) [x1,y1,x2,y2,class]
    float* __restrict__ ws)
{
    __shared__ float m_s[APB];          // per-anchor multiplier: 0 (ignore) or -0.75*ln2
    __shared__ float red_c[4], red_r[4], red_n[4];

    const int b   = blockIdx.y;
    const int a0  = blockIdx.x * APB;
    const int tid = threadIdx.x;
    const int nA  = min(APB, A_TOTAL - a0);
    const float* __restrict__ annb = ann + b * (M_ANN * 5);  // uniform -> s_load

    float r_acc = 0.0f, n_acc = 0.0f, c_acc = 0.0f;
    float mval  = 0.0f;

    // ---- Phase 1: IoU argmax (division-free), state, GIoU + focal correction for positives ----
    if (tid < nA) {
        const int a = a0 + tid;
        float4 anc = ((const float4*)anchors)[a];
        float ay1 = anc.x, ax1 = anc.y, ay2 = anc.z, ax2 = anc.w;
        float area_a = (ay2 - ay1) * (ax2 - ax1);
        float binter = 0.0f, bua = 1.0f;
        int   barg = 0;
        #pragma unroll
        for (int j = 0; j < M_ANN; ++j) {
            float bx1 = annb[j * 5 + 0], by1 = annb[j * 5 + 1];
            float bx2 = annb[j * 5 + 2], by2 = annb[j * 5 + 3];
            float iw = fmaxf(fminf(ax2, bx2) - fmaxf(ax1, bx1), 0.0f);
            float ih = fmaxf(fminf(ay2, by2) - fmaxf(ay1, by1), 0.0f);
            float inter = iw * ih;
            float ua = fmaxf(area_a + (bx2 - bx1) * (by2 - by1) - inter, 1e-8f);
            bool gt = inter * bua > binter * ua;   // iou_j > iou_best, division-free
            binter = gt ? inter : binter;
            bua    = gt ? ua    : bua;
            barg   = gt ? j     : barg;            // strict > keeps FIRST max
        }
        bool pos = binter >= 0.5f * bua;
        bool neg = binter <  0.4f * bua;
        mval = (pos || neg) ? NEG075LN2 : 0.0f;    // ignore band -> 0

        if (pos) {
            n_acc = 1.0f;
            int k = (int)annb[barg * 5 + 4];
            float cv = cls[((size_t)b * A_TOTAL + a) * C_CLS + k];
            float c  = fminf(fmaxf(cv, 5e-4f), 1.0f - 5e-4f);
            float omc = 1.0f - c;
            c_acc += 0.25f * omc * omc * (-__logf(c))
                   - 0.75f * c * c * (-__logf(omc));

            float4 rg = ((const float4*)reg)[(size_t)b * A_TOTAL + a];
            float ty = rg.x, tx = rg.y, th = rg.z, tw = rg.w;
            float aw = ax2 - ax1, ah = ay2 - ay1;
            float acx = ax1 + 0.5f * aw, acy = ay1 + 0.5f * ah;
            float pcx = tx * aw + acx, pcy = ty * ah + acy;
            float pw = __expf(tw) * aw, ph = __expf(th) * ah;
            float px1 = fmaxf(pcx - 0.5f * pw, 0.0f);
            float py1 = fmaxf(pcy - 0.5f * ph, 0.0f);
            float px2 = fmaxf(pcx + 0.5f * pw, 0.0f);
            float py2 = fmaxf(pcy + 0.5f * ph, 0.0f);
            float gx1 = fmaxf(annb[barg * 5 + 0], 0.0f);
            float gy1 = fmaxf(annb[barg * 5 + 1], 0.0f);
            float gx2 = fmaxf(annb[barg * 5 + 2], 0.0f);
            float gy2 = fmaxf(annb[barg * 5 + 3], 0.0f);
            float iw2 = fmaxf(fminf(px2, gx2) - fmaxf(px1, gx1), 0.0f);
            float ih2 = fmaxf(fminf(py2, gy2) - fmaxf(py1, gy1), 0.0f);
            float inter2 = iw2 * ih2;
            float area_p = fmaxf((px2 - px1) * (py2 - py1), 1e-6f);
            float area_g = fmaxf((gx2 - gx1) * (gy2 - gy1), 1e-6f);
            float uni = area_p + area_g - inter2;
            float iou2 = inter2 / (uni + 1e-7f);
            float wc = fmaxf(fmaxf(px2, gx2) - fminf(px1, gx1), 1e-6f);
            float hc = fmaxf(fmaxf(py2, gy2) - fminf(py1, gy1), 1e-6f);
            float area_c = wc * hc;
            float giou = fminf(fmaxf(iou2 - (area_c - uni) / (area_c + 1e-7f), -1.0f), 1.0f);
            r_acc = 1.0f - giou;
        }
    }
    m_s[tid] = (tid < nA) ? mval : 0.0f;
    __syncthreads();

    // ---- Phase 2: streaming focal loss, 10 loads in flight per wave ----
    const float4* __restrict__ cp =
        (const float4*)(cls + ((size_t)b * A_TOTAL + a0) * C_CLS);

#define FOCAL4(v, idx)                                                    \
    {                                                                     \
        float m_ = m_s[(unsigned)(idx) / 20u];                            \
        float s_, c_;                                                     \
        c_ = fminf(fmaxf((v).x, 5e-4f), 1.0f - 5e-4f);                    \
        s_ = c_ * c_ * __log2f(1.0f - c_);                                \
        c_ = fminf(fmaxf((v).y, 5e-4f), 1.0f - 5e-4f);                    \
        s_ = fmaf(c_ * c_, __log2f(1.0f - c_), s_);                       \
        c_ = fminf(fmaxf((v).z, 5e-4f), 1.0f - 5e-4f);                    \
        s_ = fmaf(c_ * c_, __log2f(1.0f - c_), s_);                       \
        c_ = fminf(fmaxf((v).w, 5e-4f), 1.0f - 5e-4f);                    \
        s_ = fmaf(c_ * c_, __log2f(1.0f - c_), s_);                       \
        c_acc = fmaf(m_, s_, c_acc);                                      \
    }

    if (nA == APB) {
        // full block: 5120 float4, 20 per thread, 2 groups of 10 deep loads
        #pragma unroll
        for (int g = 0; g < 2; ++g) {
            const int base = tid + g * 2560;
            float4 v0 = cp[base];
            float4 v1 = cp[base + 256];
            float4 v2 = cp[base + 512];
            float4 v3 = cp[base + 768];
            float4 v4 = cp[base + 1024];
            float4 v5 = cp[base + 1280];
            float4 v6 = cp[base + 1536];
            float4 v7 = cp[base + 1792];
            float4 v8 = cp[base + 2048];
            float4 v9 = cp[base + 2304];
            FOCAL4(v0, base)
            FOCAL4(v1, base + 256)
            FOCAL4(v2, base + 512)
            FOCAL4(v3, base + 768)
            FOCAL4(v4, base + 1024)
            FOCAL4(v5, base + 1280)
            FOCAL4(v6, base + 1536)
            FOCAL4(v7, base + 1792)
            FOCAL4(v8, base + 2048)
            FOCAL4(v9, base + 2304)
        }
    } else {
        const int nf4 = nA * (C_CLS / 4);
        for (int i = tid; i < nf4; i += THREADS) {
            float4 v = cp[i];
            FOCAL4(v, i)
        }
    }
#undef FOCAL4

    // ---- Block reduction + per-image atomics ----
    #pragma unroll
    for (int o = 32; o > 0; o >>= 1) {
        c_acc += __shfl_down(c_acc, o);
        r_acc += __shfl_down(r_acc, o);
        n_acc += __shfl_down(n_acc, o);
    }
    int wid = tid >> 6;
    if ((tid & 63) == 0) { red_c[wid] = c_acc; red_r[wid] = r_acc; red_n[wid] = n_acc; }
    __syncthreads();
    if (tid == 0) {
        atomicAdd(&ws[b],             red_c[0] + red_c[1] + red_c[2] + red_c[3]);
        atomicAdd(&ws[B_IMG + b],     red_r[0] + red_r[1] + red_r[2] + red_r[3]);
        atomicAdd(&ws[2 * B_IMG + b], red_n[0] + red_n[1] + red_n[2] + red_n[3]);
    }
}

__global__ void finalize_kernel(const float* __restrict__ ws, float* __restrict__ out) {
    if (threadIdx.x == 0) {
        float c = 0.0f, r = 0.0f;
        for (int b = 0; b < B_IMG; ++b) {
            float n = ws[2 * B_IMG + b];
            c += ws[b] / fmaxf(n, 1.0f);
            r += (n > 0.0f) ? (ws[B_IMG + b] / fmaxf(n, 1.0f)) : 0.0f;
        }
        c *= (1.0f / B_IMG);
        r *= (1.0f / B_IMG);
        out[0] = c + r;
        out[1] = c;
        out[2] = r;
    }
}

extern "C" void kernel_launch(void* const* d_in, const int* in_sizes, int n_in,
                              void* d_out, int out_size, void* d_ws, size_t ws_size,
                              hipStream_t stream) {
    const float* cls     = (const float*)d_in[0];
    const float* reg     = (const float*)d_in[1];
    const float* anchors = (const float*)d_in[2];
    const float* ann     = (const float*)d_in[3];
    float* ws  = (float*)d_ws;
    float* out = (float*)d_out;

    hipLaunchKernelGGL(init_ws_kernel, dim3(1), dim3(64), 0, stream, ws);
    dim3 grid((A_TOTAL + APB - 1) / APB, B_IMG);
    hipLaunchKernelGGL(focal_main_kernel, grid, dim3(THREADS), 0, stream,
                       cls, reg, anchors, ann, ws);
    hipLaunchKernelGGL(finalize_kernel, dim3(1), dim3(64), 0, stream, ws, out);
}

// Round 5
// 69.831 us; speedup vs baseline: 2.5867x; 1.8250x over previous
//
#include <hip/hip_runtime.h>

#define B_IMG 8
#define A_TOTAL 120000
#define C_CLS 80
#define M_ANN 32
#define APB 256      // anchors per block
#define THREADS 256
#define NBLK_X 469                     // ceil(120000/256)
#define NBLK   (NBLK_X * B_IMG)        // 3752 blocks
#define NEG075LN2 (-0.51986038542f)    // -0.75 * ln(2)

// ws layout (floats), all rewritten every call (no init needed):
//   [0        .. NBLK)    per-block c partial
//   [NBLK     .. 2*NBLK)  per-block r partial
//   [2*NBLK   .. 3*NBLK)  per-block n partial
__global__ __launch_bounds__(THREADS) void focal_main_kernel(
    const float* __restrict__ cls,      // (B, A, C)
    const float* __restrict__ reg,      // (B, A, 4)
    const float* __restrict__ anchors,  // (A, 4)  [y1,x1,y2,x2]
    const float* __restrict__ ann,      // (B, M, 5) [x1,y1,x2,y2,class]
    float* __restrict__ ws)
{
    __shared__ float m_s[APB];          // per-anchor multiplier: 0 (ignore) or -0.75*ln2
    __shared__ float red_c[4], red_r[4], red_n[4];

    const int b   = blockIdx.y;
    const int a0  = blockIdx.x * APB;
    const int tid = threadIdx.x;
    const int nA  = min(APB, A_TOTAL - a0);
    const float* __restrict__ annb = ann + b * (M_ANN * 5);  // uniform -> s_load

    float r_acc = 0.0f, n_acc = 0.0f, c_acc = 0.0f;
    float mval  = 0.0f;

    // ---- Phase 1: IoU argmax (division-free), state, GIoU + focal correction for positives ----
    if (tid < nA) {
        const int a = a0 + tid;
        float4 anc = ((const float4*)anchors)[a];
        float ay1 = anc.x, ax1 = anc.y, ay2 = anc.z, ax2 = anc.w;
        float area_a = (ay2 - ay1) * (ax2 - ax1);
        float binter = 0.0f, bua = 1.0f;
        int   barg = 0;
        #pragma unroll
        for (int j = 0; j < M_ANN; ++j) {
            float bx1 = annb[j * 5 + 0], by1 = annb[j * 5 + 1];
            float bx2 = annb[j * 5 + 2], by2 = annb[j * 5 + 3];
            float iw = fmaxf(fminf(ax2, bx2) - fmaxf(ax1, bx1), 0.0f);
            float ih = fmaxf(fminf(ay2, by2) - fmaxf(ay1, by1), 0.0f);
            float inter = iw * ih;
            float ua = fmaxf(area_a + (bx2 - bx1) * (by2 - by1) - inter, 1e-8f);
            bool gt = inter * bua > binter * ua;   // iou_j > iou_best, division-free
            binter = gt ? inter : binter;
            bua    = gt ? ua    : bua;
            barg   = gt ? j     : barg;            // strict > keeps FIRST max
        }
        bool pos = binter >= 0.5f * bua;
        bool neg = binter <  0.4f * bua;
        mval = (pos || neg) ? NEG075LN2 : 0.0f;    // ignore band -> 0

        if (pos) {
            n_acc = 1.0f;
            int k = (int)annb[barg * 5 + 4];
            float cv = cls[((size_t)b * A_TOTAL + a) * C_CLS + k];
            float c  = fminf(fmaxf(cv, 5e-4f), 1.0f - 5e-4f);
            float omc = 1.0f - c;
            c_acc += 0.25f * omc * omc * (-__logf(c))
                   - 0.75f * c * c * (-__logf(omc));

            float4 rg = ((const float4*)reg)[(size_t)b * A_TOTAL + a];
            float ty = rg.x, tx = rg.y, th = rg.z, tw = rg.w;
            float aw = ax2 - ax1, ah = ay2 - ay1;
            float acx = ax1 + 0.5f * aw, acy = ay1 + 0.5f * ah;
            float pcx = tx * aw + acx, pcy = ty * ah + acy;
            float pw = __expf(tw) * aw, ph = __expf(th) * ah;
            float px1 = fmaxf(pcx - 0.5f * pw, 0.0f);
            float py1 = fmaxf(pcy - 0.5f * ph, 0.0f);
            float px2 = fmaxf(pcx + 0.5f * pw, 0.0f);
            float py2 = fmaxf(pcy + 0.5f * ph, 0.0f);
            float gx1 = fmaxf(annb[barg * 5 + 0], 0.0f);
            float gy1 = fmaxf(annb[barg * 5 + 1], 0.0f);
            float gx2 = fmaxf(annb[barg * 5 + 2], 0.0f);
            float gy2 = fmaxf(annb[barg * 5 + 3], 0.0f);
            float iw2 = fmaxf(fminf(px2, gx2) - fmaxf(px1, gx1), 0.0f);
            float ih2 = fmaxf(fminf(py2, gy2) - fmaxf(py1, gy1), 0.0f);
            float inter2 = iw2 * ih2;
            float area_p = fmaxf((px2 - px1) * (py2 - py1), 1e-6f);
            float area_g = fmaxf((gx2 - gx1) * (gy2 - gy1), 1e-6f);
            float uni = area_p + area_g - inter2;
            float iou2 = inter2 / (uni + 1e-7f);
            float wc = fmaxf(fmaxf(px2, gx2) - fminf(px1, gx1), 1e-6f);
            float hc = fmaxf(fmaxf(py2, gy2) - fminf(py1, gy1), 1e-6f);
            float area_c = wc * hc;
            float giou = fminf(fmaxf(iou2 - (area_c - uni) / (area_c + 1e-7f), -1.0f), 1.0f);
            r_acc = 1.0f - giou;
        }
    }
    m_s[tid] = (tid < nA) ? mval : 0.0f;
    __syncthreads();

    // ---- Phase 2: streaming focal loss, 10 loads in flight per wave ----
    const float4* __restrict__ cp =
        (const float4*)(cls + ((size_t)b * A_TOTAL + a0) * C_CLS);

#define FOCAL4(v, idx)                                                    \
    {                                                                     \
        float m_ = m_s[(unsigned)(idx) / 20u];                            \
        float s_, c_;                                                     \
        c_ = fminf(fmaxf((v).x, 5e-4f), 1.0f - 5e-4f);                    \
        s_ = c_ * c_ * __log2f(1.0f - c_);                                \
        c_ = fminf(fmaxf((v).y, 5e-4f), 1.0f - 5e-4f);                    \
        s_ = fmaf(c_ * c_, __log2f(1.0f - c_), s_);                       \
        c_ = fminf(fmaxf((v).z, 5e-4f), 1.0f - 5e-4f);                    \
        s_ = fmaf(c_ * c_, __log2f(1.0f - c_), s_);                       \
        c_ = fminf(fmaxf((v).w, 5e-4f), 1.0f - 5e-4f);                    \
        s_ = fmaf(c_ * c_, __log2f(1.0f - c_), s_);                       \
        c_acc = fmaf(m_, s_, c_acc);                                      \
    }

    if (nA == APB) {
        // full block: 5120 float4, 20 per thread, 2 groups of 10 deep loads
        #pragma unroll
        for (int g = 0; g < 2; ++g) {
            const int base = tid + g * 2560;
            float4 v0 = cp[base];
            float4 v1 = cp[base + 256];
            float4 v2 = cp[base + 512];
            float4 v3 = cp[base + 768];
            float4 v4 = cp[base + 1024];
            float4 v5 = cp[base + 1280];
            float4 v6 = cp[base + 1536];
            float4 v7 = cp[base + 1792];
            float4 v8 = cp[base + 2048];
            float4 v9 = cp[base + 2304];
            FOCAL4(v0, base)
            FOCAL4(v1, base + 256)
            FOCAL4(v2, base + 512)
            FOCAL4(v3, base + 768)
            FOCAL4(v4, base + 1024)
            FOCAL4(v5, base + 1280)
            FOCAL4(v6, base + 1536)
            FOCAL4(v7, base + 1792)
            FOCAL4(v8, base + 2048)
            FOCAL4(v9, base + 2304)
        }
    } else {
        const int nf4 = nA * (C_CLS / 4);
        for (int i = tid; i < nf4; i += THREADS) {
            float4 v = cp[i];
            FOCAL4(v, i)
        }
    }
#undef FOCAL4

    // ---- Block reduction + NON-ATOMIC per-block slot write ----
    #pragma unroll
    for (int o = 32; o > 0; o >>= 1) {
        c_acc += __shfl_down(c_acc, o);
        r_acc += __shfl_down(r_acc, o);
        n_acc += __shfl_down(n_acc, o);
    }
    int wid = tid >> 6;
    if ((tid & 63) == 0) { red_c[wid] = c_acc; red_r[wid] = r_acc; red_n[wid] = n_acc; }
    __syncthreads();
    if (tid == 0) {
        const int slot = b * NBLK_X + blockIdx.x;
        ws[slot]            = red_c[0] + red_c[1] + red_c[2] + red_c[3];
        ws[NBLK + slot]     = red_r[0] + red_r[1] + red_r[2] + red_r[3];
        ws[2 * NBLK + slot] = red_n[0] + red_n[1] + red_n[2] + red_n[3];
    }
}

__global__ __launch_bounds__(THREADS) void finalize_kernel(
    const float* __restrict__ ws, float* __restrict__ out)
{
    __shared__ float red[4][3];
    const int tid = threadIdx.x;
    float c_tot = 0.0f, r_tot = 0.0f;   // only meaningful on tid 0

    for (int b = 0; b < B_IMG; ++b) {
        float pc = 0.0f, pr = 0.0f, pn = 0.0f;
        for (int i = tid; i < NBLK_X; i += THREADS) {
            const int slot = b * NBLK_X + i;
            pc += ws[slot];
            pr += ws[NBLK + slot];
            pn += ws[2 * NBLK + slot];
        }
        #pragma unroll
        for (int o = 32; o > 0; o >>= 1) {
            pc += __shfl_down(pc, o);
            pr += __shfl_down(pr, o);
            pn += __shfl_down(pn, o);
        }
        if ((tid & 63) == 0) {
            int wid = tid >> 6;
            red[wid][0] = pc; red[wid][1] = pr; red[wid][2] = pn;
        }
        __syncthreads();
        if (tid == 0) {
            float cs = red[0][0] + red[1][0] + red[2][0] + red[3][0];
            float rs = red[0][1] + red[1][1] + red[2][1] + red[3][1];
            float ns = red[0][2] + red[1][2] + red[2][2] + red[3][2];
            c_tot += cs / fmaxf(ns, 1.0f);
            r_tot += (ns > 0.0f) ? (rs / fmaxf(ns, 1.0f)) : 0.0f;
        }
        __syncthreads();
    }
    if (tid == 0) {
        c_tot *= (1.0f / B_IMG);
        r_tot *= (1.0f / B_IMG);
        out[0] = c_tot + r_tot;
        out[1] = c_tot;
        out[2] = r_tot;
    }
}

extern "C" void kernel_launch(void* const* d_in, const int* in_sizes, int n_in,
                              void* d_out, int out_size, void* d_ws, size_t ws_size,
                              hipStream_t stream) {
    const float* cls     = (const float*)d_in[0];
    const float* reg     = (const float*)d_in[1];
    const float* anchors = (const float*)d_in[2];
    const float* ann     = (const float*)d_in[3];
    float* ws  = (float*)d_ws;
    float* out = (float*)d_out;

    dim3 grid(NBLK_X, B_IMG);
    hipLaunchKernelGGL(focal_main_kernel, grid, dim3(THREADS), 0, stream,
                       cls, reg, anchors, ann, ws);
    hipLaunchKernelGGL(finalize_kernel, dim3(1), dim3(THREADS), 0, stream, ws, out);
}

// Round 6
// 68.849 us; speedup vs baseline: 2.6236x; 1.0143x over previous
//
#include <hip/hip_runtime.h>

#define B_IMG 8
#define A_TOTAL 120000
#define C_CLS 80
#define M_ANN 32
#define APB 256      // anchors per block
#define THREADS 256
#define NBLK_X 469                     // ceil(120000/256)
#define NBLK   (NBLK_X * B_IMG)        // 3752 blocks
#define NEG075LN2 (-0.51986038542f)    // -0.75 * ln(2)

// ws layout (floats), all rewritten every call (no init needed):
//   [0        .. NBLK)    per-block c partial
//   [NBLK     .. 2*NBLK)  per-block r partial
//   [2*NBLK   .. 3*NBLK)  per-block n partial
__global__ __launch_bounds__(THREADS) void focal_main_kernel(
    const float* __restrict__ cls,      // (B, A, C)
    const float* __restrict__ reg,      // (B, A, 4)
    const float* __restrict__ anchors,  // (A, 4)  [y1,x1,y2,x2]
    const float* __restrict__ ann,      // (B, M, 5) [x1,y1,x2,y2,class]
    float* __restrict__ ws)
{
    __shared__ float m_s[APB];          // per-anchor multiplier: 0 (ignore) or -0.75*ln2
    __shared__ float red_c[4], red_r[4], red_n[4];

    const int b   = blockIdx.y;
    const int a0  = blockIdx.x * APB;
    const int tid = threadIdx.x;
    const int nA  = min(APB, A_TOTAL - a0);
    const float* __restrict__ annb = ann + b * (M_ANN * 5);  // uniform -> s_load

    float r_acc = 0.0f, n_acc = 0.0f, c_acc = 0.0f;
    float mval  = 0.0f;
    const bool full = (nA == APB);

    const float4* __restrict__ cp =
        (const float4*)(cls + ((size_t)b * A_TOTAL + a0) * C_CLS);

    // ---- Issue group-0 streaming loads FIRST (independent of phase 1) ----
    float4 v0, v1, v2, v3, v4, v5, v6, v7, v8, v9;
    if (full) {
        v0 = cp[tid];
        v1 = cp[tid + 256];
        v2 = cp[tid + 512];
        v3 = cp[tid + 768];
        v4 = cp[tid + 1024];
        v5 = cp[tid + 1280];
        v6 = cp[tid + 1536];
        v7 = cp[tid + 1792];
        v8 = cp[tid + 2048];
        v9 = cp[tid + 2304];
    }

    // ---- Phase 1: IoU argmax (division-free), state, GIoU + focal correction for positives ----
    if (tid < nA) {
        const int a = a0 + tid;
        float4 anc = ((const float4*)anchors)[a];
        float ay1 = anc.x, ax1 = anc.y, ay2 = anc.z, ax2 = anc.w;
        float area_a = (ay2 - ay1) * (ax2 - ax1);
        float binter = 0.0f, bua = 1.0f;
        int   barg = 0;
        #pragma unroll
        for (int j = 0; j < M_ANN; ++j) {
            float bx1 = annb[j * 5 + 0], by1 = annb[j * 5 + 1];
            float bx2 = annb[j * 5 + 2], by2 = annb[j * 5 + 3];
            float iw = fmaxf(fminf(ax2, bx2) - fmaxf(ax1, bx1), 0.0f);
            float ih = fmaxf(fminf(ay2, by2) - fmaxf(ay1, by1), 0.0f);
            float inter = iw * ih;
            float ua = fmaxf(area_a + (bx2 - bx1) * (by2 - by1) - inter, 1e-8f);
            bool gt = inter * bua > binter * ua;   // iou_j > iou_best, division-free
            binter = gt ? inter : binter;
            bua    = gt ? ua    : bua;
            barg   = gt ? j     : barg;            // strict > keeps FIRST max
        }
        bool pos = binter >= 0.5f * bua;
        bool neg = binter <  0.4f * bua;
        mval = (pos || neg) ? NEG075LN2 : 0.0f;    // ignore band -> 0

        if (pos) {
            n_acc = 1.0f;
            int k = (int)annb[barg * 5 + 4];
            float cv = cls[((size_t)b * A_TOTAL + a) * C_CLS + k];
            float c  = fminf(fmaxf(cv, 5e-4f), 1.0f - 5e-4f);
            float omc = 1.0f - c;
            c_acc += 0.25f * omc * omc * (-__logf(c))
                   - 0.75f * c * c * (-__logf(omc));

            float4 rg = ((const float4*)reg)[(size_t)b * A_TOTAL + a];
            float ty = rg.x, tx = rg.y, th = rg.z, tw = rg.w;
            float aw = ax2 - ax1, ah = ay2 - ay1;
            float acx = ax1 + 0.5f * aw, acy = ay1 + 0.5f * ah;
            float pcx = tx * aw + acx, pcy = ty * ah + acy;
            float pw = __expf(tw) * aw, ph = __expf(th) * ah;
            float px1 = fmaxf(pcx - 0.5f * pw, 0.0f);
            float py1 = fmaxf(pcy - 0.5f * ph, 0.0f);
            float px2 = fmaxf(pcx + 0.5f * pw, 0.0f);
            float py2 = fmaxf(pcy + 0.5f * ph, 0.0f);
            float gx1 = fmaxf(annb[barg * 5 + 0], 0.0f);
            float gy1 = fmaxf(annb[barg * 5 + 1], 0.0f);
            float gx2 = fmaxf(annb[barg * 5 + 2], 0.0f);
            float gy2 = fmaxf(annb[barg * 5 + 3], 0.0f);
            float iw2 = fmaxf(fminf(px2, gx2) - fmaxf(px1, gx1), 0.0f);
            float ih2 = fmaxf(fminf(py2, gy2) - fmaxf(py1, gy1), 0.0f);
            float inter2 = iw2 * ih2;
            float area_p = fmaxf((px2 - px1) * (py2 - py1), 1e-6f);
            float area_g = fmaxf((gx2 - gx1) * (gy2 - gy1), 1e-6f);
            float uni = area_p + area_g - inter2;
            float iou2 = inter2 / (uni + 1e-7f);
            float wc = fmaxf(fmaxf(px2, gx2) - fminf(px1, gx1), 1e-6f);
            float hc = fmaxf(fmaxf(py2, gy2) - fminf(py1, gy1), 1e-6f);
            float area_c = wc * hc;
            float giou = fminf(fmaxf(iou2 - (area_c - uni) / (area_c + 1e-7f), -1.0f), 1.0f);
            r_acc = 1.0f - giou;
        }
    }
    m_s[tid] = (tid < nA) ? mval : 0.0f;
    __syncthreads();

#define FOCAL4(v, idx)                                                    \
    {                                                                     \
        float m_ = m_s[(unsigned)(idx) / 20u];                            \
        float s_, c_;                                                     \
        c_ = fminf(fmaxf((v).x, 5e-4f), 1.0f - 5e-4f);                    \
        s_ = c_ * c_ * __log2f(1.0f - c_);                                \
        c_ = fminf(fmaxf((v).y, 5e-4f), 1.0f - 5e-4f);                    \
        s_ = fmaf(c_ * c_, __log2f(1.0f - c_), s_);                       \
        c_ = fminf(fmaxf((v).z, 5e-4f), 1.0f - 5e-4f);                    \
        s_ = fmaf(c_ * c_, __log2f(1.0f - c_), s_);                       \
        c_ = fminf(fmaxf((v).w, 5e-4f), 1.0f - 5e-4f);                    \
        s_ = fmaf(c_ * c_, __log2f(1.0f - c_), s_);                       \
        c_acc = fmaf(m_, s_, c_acc);                                      \
    }

    if (full) {
        // group 0: consume the pre-issued loads
        FOCAL4(v0, tid)
        FOCAL4(v1, tid + 256)
        FOCAL4(v2, tid + 512)
        FOCAL4(v3, tid + 768)
        FOCAL4(v4, tid + 1024)
        FOCAL4(v5, tid + 1280)
        FOCAL4(v6, tid + 1536)
        FOCAL4(v7, tid + 1792)
        FOCAL4(v8, tid + 2048)
        FOCAL4(v9, tid + 2304)
        // group 1: 10 more deep loads
        const int base = tid + 2560;
        v0 = cp[base];
        v1 = cp[base + 256];
        v2 = cp[base + 512];
        v3 = cp[base + 768];
        v4 = cp[base + 1024];
        v5 = cp[base + 1280];
        v6 = cp[base + 1536];
        v7 = cp[base + 1792];
        v8 = cp[base + 2048];
        v9 = cp[base + 2304];
        FOCAL4(v0, base)
        FOCAL4(v1, base + 256)
        FOCAL4(v2, base + 512)
        FOCAL4(v3, base + 768)
        FOCAL4(v4, base + 1024)
        FOCAL4(v5, base + 1280)
        FOCAL4(v6, base + 1536)
        FOCAL4(v7, base + 1792)
        FOCAL4(v8, base + 2048)
        FOCAL4(v9, base + 2304)
    } else {
        const int nf4 = nA * (C_CLS / 4);
        for (int i = tid; i < nf4; i += THREADS) {
            float4 v = cp[i];
            FOCAL4(v, i)
        }
    }
#undef FOCAL4

    // ---- Block reduction + NON-ATOMIC per-block slot write ----
    #pragma unroll
    for (int o = 32; o > 0; o >>= 1) {
        c_acc += __shfl_down(c_acc, o);
        r_acc += __shfl_down(r_acc, o);
        n_acc += __shfl_down(n_acc, o);
    }
    int wid = tid >> 6;
    if ((tid & 63) == 0) { red_c[wid] = c_acc; red_r[wid] = r_acc; red_n[wid] = n_acc; }
    __syncthreads();
    if (tid == 0) {
        const int slot = b * NBLK_X + blockIdx.x;
        ws[slot]            = red_c[0] + red_c[1] + red_c[2] + red_c[3];
        ws[NBLK + slot]     = red_r[0] + red_r[1] + red_r[2] + red_r[3];
        ws[2 * NBLK + slot] = red_n[0] + red_n[1] + red_n[2] + red_n[3];
    }
}

// One pass, 32 threads per image (8 images x 32 lanes = 256 threads).
__global__ __launch_bounds__(THREADS) void finalize_kernel(
    const float* __restrict__ ws, float* __restrict__ out)
{
    __shared__ float sc[B_IMG], sr[B_IMG], sn[B_IMG];
    const int tid    = threadIdx.x;
    const int img    = tid >> 5;        // 0..7
    const int lane32 = tid & 31;

    float pc = 0.0f, pr = 0.0f, pn = 0.0f;
    for (int i = lane32; i < NBLK_X; i += 32) {
        const int slot = img * NBLK_X + i;
        pc += ws[slot];
        pr += ws[NBLK + slot];
        pn += ws[2 * NBLK + slot];
    }
    #pragma unroll
    for (int o = 16; o > 0; o >>= 1) {
        pc += __shfl_down(pc, o, 32);
        pr += __shfl_down(pr, o, 32);
        pn += __shfl_down(pn, o, 32);
    }
    if (lane32 == 0) { sc[img] = pc; sr[img] = pr; sn[img] = pn; }
    __syncthreads();
    if (tid == 0) {
        float c_tot = 0.0f, r_tot = 0.0f;
        #pragma unroll
        for (int b = 0; b < B_IMG; ++b) {
            float ns = sn[b];
            c_tot += sc[b] / fmaxf(ns, 1.0f);
            r_tot += (ns > 0.0f) ? (sr[b] / fmaxf(ns, 1.0f)) : 0.0f;
        }
        c_tot *= (1.0f / B_IMG);
        r_tot *= (1.0f / B_IMG);
        out[0] = c_tot + r_tot;
        out[1] = c_tot;
        out[2] = r_tot;
    }
}

extern "C" void kernel_launch(void* const* d_in, const int* in_sizes, int n_in,
                              void* d_out, int out_size, void* d_ws, size_t ws_size,
                              hipStream_t stream) {
    const float* cls     = (const float*)d_in[0];
    const float* reg     = (const float*)d_in[1];
    const float* anchors = (const float*)d_in[2];
    const float* ann     = (const float*)d_in[3];
    float* ws  = (float*)d_ws;
    float* out = (float*)d_out;

    dim3 grid(NBLK_X, B_IMG);
    hipLaunchKernelGGL(focal_main_kernel, grid, dim3(THREADS), 0, stream,
                       cls, reg, anchors, ann, ws);
    hipLaunchKernelGGL(finalize_kernel, dim3(1), dim3(THREADS), 0, stream, ws, out);
}